// Round 1
// baseline (56.353 us; speedup 1.0000x reference)
//
#include <hip/hip_runtime.h>
#include <math.h>

#define B 2
#define T 6
#define NN 100
#define HH 128
#define WW 128
#define M 20
#define DD 256
#define HW (HH*WW)

// ws layout (floats): [0]=bce_sum [1]=dice_sum [2]=match_sum [3]=ctr_sum

__device__ __forceinline__ float wave_reduce(float v) {
    #pragma unroll
    for (int o = 32; o > 0; o >>= 1) v += __shfl_down(v, o, 64);
    return v;
}

__device__ __forceinline__ float wave_allreduce(float v) {
    #pragma unroll
    for (int o = 1; o < 64; o <<= 1) v += __shfl_xor(v, o, 64);
    return v;
}

__global__ void zero_acc_kernel(float* __restrict__ acc) {
    if (threadIdx.x < 4) acc[threadIdx.x] = 0.0f;
}

// One block per (t,b,m): full plane reduction (16384 px), 1024 threads = 16 waves.
__global__ __launch_bounds__(1024) void mask_dice_kernel(
        const float* __restrict__ pred_masks,
        const float* __restrict__ gt_masks,
        const int* __restrict__ perm,
        float* __restrict__ acc) {
    int bid = blockIdx.x;            // t*(B*M) + b*M + m
    int m = bid % M;
    int b = (bid / M) % B;
    int t = bid / (B * M);
    int n = perm[(t * B + b) * M + m];
    const float4* src = (const float4*)(pred_masks + (((size_t)b * T + t) * NN + n) * HW);
    const float4* tgt = (const float4*)(gt_masks   + (((size_t)b * T + t) * M  + m) * HW);

    float bce = 0.f, st = 0.f, ss = 0.f, ts = 0.f;
    for (int i = threadIdx.x; i < HW / 4; i += 1024) {
        float4 s4 = src[i];
        float4 t4 = tgt[i];
        const float* sp = &s4.x;
        const float* tp = &t4.x;
        #pragma unroll
        for (int j = 0; j < 4; ++j) {
            float x = sp[j];
            float y = tp[j];
            bce += fmaxf(x, 0.f) - x * y + log1pf(expf(-fabsf(x)));
            float sg = 1.f / (1.f + expf(-x));
            st += sg * y;
            ss += sg;
            ts += y;
        }
    }

    __shared__ float red[16][4];
    int lane = threadIdx.x & 63, wid = threadIdx.x >> 6;
    bce = wave_reduce(bce);
    st  = wave_reduce(st);
    ss  = wave_reduce(ss);
    ts  = wave_reduce(ts);
    if (lane == 0) { red[wid][0] = bce; red[wid][1] = st; red[wid][2] = ss; red[wid][3] = ts; }
    __syncthreads();
    if (threadIdx.x == 0) {
        float a0 = 0.f, a1 = 0.f, a2 = 0.f, a3 = 0.f;
        #pragma unroll
        for (int wv = 0; wv < 16; ++wv) { a0 += red[wv][0]; a1 += red[wv][1]; a2 += red[wv][2]; a3 += red[wv][3]; }
        atomicAdd(&acc[0], a0);
        float dice = 1.f - 2.f * a1 / (a2 + a3 + 1e-6f);
        atomicAdd(&acc[1], dice);
    }
}

// One block per (t,b), t in [0, T-1): normalize gathered embeddings, sim = curr·nxt^T,
// two log-softmaxes over the 20-wide rows, accumulate -diag.
__global__ __launch_bounds__(256) void emb_kernel(
        const float* __restrict__ pred_embs,
        const int* __restrict__ perm,
        float* __restrict__ acc) {
    int b = blockIdx.x % B;
    int t = blockIdx.x / B;          // 0..T-2
    __shared__ float cur[M][DD];
    __shared__ float nxt[M][DD];
    __shared__ float sim[M][M + 1];
    int lane = threadIdx.x & 63, wid = threadIdx.x >> 6;

    // 40 vectors, 4 waves: each wave normalizes 10 vectors (64 lanes x float4 = 256 elems)
    for (int v = wid; v < 2 * M; v += 4) {
        int tt = (v < M) ? t : (t + 1);
        int m  = (v < M) ? v : (v - M);
        int n  = perm[(tt * B + b) * M + m];
        const float4* srcp = (const float4*)(pred_embs + (((size_t)b * T + tt) * NN + n) * DD);
        float4 x = srcp[lane];
        float sq = x.x * x.x + x.y * x.y + x.z * x.z + x.w * x.w;
        sq = wave_allreduce(sq);
        float inv = 1.f / fmaxf(sqrtf(sq), 1e-12f);
        float* dst = (v < M) ? &cur[m][0] : &nxt[m][0];
        ((float4*)dst)[lane] = make_float4(x.x * inv, x.y * inv, x.z * inv, x.w * inv);
    }
    __syncthreads();

    for (int p = threadIdx.x; p < M * M; p += 256) {
        int m = p / M, n = p % M;
        float d = 0.f;
        #pragma unroll 8
        for (int k = 0; k < DD; ++k) d += cur[m][k] * nxt[n][k];
        sim[m][n] = d;
    }
    __syncthreads();

    if (threadIdx.x < M) {
        int m = threadIdx.x;
        float mx = -1e30f;
        #pragma unroll
        for (int n2 = 0; n2 < M; ++n2) mx = fmaxf(mx, sim[m][n2]);
        float sa = 0.f, sc = 0.f;
        #pragma unroll
        for (int n2 = 0; n2 < M; ++n2) {
            float z = sim[m][n2] - mx;
            sa += expf(5.0f * z);    // ALPHA = 5
            sc += expf(10.0f * z);   // 1/TEMPERATURE = 10
        }
        float zd = sim[m][m] - mx;
        atomicAdd(&acc[2], logf(sa) - 5.0f * zd);    // -log_softmax(ALPHA*sim)[m,m]
        atomicAdd(&acc[3], logf(sc) - 10.0f * zd);   // -log_softmax(sim/T)[m,m]
    }
}

__global__ void finalize_kernel(const float* __restrict__ acc, float* __restrict__ out) {
    float loss_mask  = acc[0] / (float)((size_t)T * B * M * HW);
    float loss_dice  = acc[1] / (float)(T * B * M);
    float loss_match = acc[2] / (float)((T - 1) * B * M);
    float loss_ctr   = acc[3] / (float)((T - 1) * B * M);
    out[0] = loss_mask;
    out[1] = loss_dice;
    out[2] = loss_ctr;
    out[3] = loss_match;
    out[4] = 5.0f * loss_mask + 5.0f * loss_dice + 1.0f * loss_match + 0.5f * loss_ctr;
}

extern "C" void kernel_launch(void* const* d_in, const int* in_sizes, int n_in,
                              void* d_out, int out_size, void* d_ws, size_t ws_size,
                              hipStream_t stream) {
    const float* pred_masks = (const float*)d_in[0];
    const float* pred_embs  = (const float*)d_in[1];
    const float* gt_masks   = (const float*)d_in[2];
    const int*   match_perm = (const int*)d_in[3];
    float* out = (float*)d_out;
    float* acc = (float*)d_ws;

    hipLaunchKernelGGL(zero_acc_kernel, dim3(1), dim3(64), 0, stream, acc);
    hipLaunchKernelGGL(mask_dice_kernel, dim3(T * B * M), dim3(1024), 0, stream,
                       pred_masks, gt_masks, match_perm, acc);
    hipLaunchKernelGGL(emb_kernel, dim3((T - 1) * B), dim3(256), 0, stream,
                       pred_embs, match_perm, acc);
    hipLaunchKernelGGL(finalize_kernel, dim3(1), dim3(1), 0, stream, acc, out);
}

// Round 2
// 23.265 us; speedup vs baseline: 2.4222x; 2.4222x over previous
//
#include <hip/hip_runtime.h>
#include <math.h>

#define B 2
#define T 6
#define NN 100
#define HH 128
#define WW 128
#define M 20
#define DD 256
#define HW (HH*WW)

#define SPLIT 2                       // blocks per plane
#define NMASK (T*B*M*SPLIT)           // 480 mask blocks
#define NEMB ((T-1)*B)                // 10 emb blocks
#define EMB_WS_OFF (NMASK*4)          // 1920 floats

__device__ __forceinline__ float wave_reduce(float v) {
    #pragma unroll
    for (int o = 32; o > 0; o >>= 1) v += __shfl_down(v, o, 64);
    return v;
}

__device__ __forceinline__ float wave_allreduce(float v) {
    #pragma unroll
    for (int o = 1; o < 64; o <<= 1) v += __shfl_xor(v, o, 64);
    return v;
}

__device__ __forceinline__ float fast_rcp(float x) {
    return __builtin_amdgcn_rcpf(x);
}

// px: process one (x,y) pair into the 4 accumulators
__device__ __forceinline__ void px(float x, float y, float& bce, float& st, float& ss, float& ts) {
    float e   = __expf(-fabsf(x));        // exp(-|x|) in (0,1]
    float rcp = fast_rcp(1.f + e);
    float sg  = (x >= 0.f) ? rcp : e * rcp;   // sigmoid(x)
    bce += fmaxf(x, 0.f) - x * y + __logf(1.f + e);
    st  += sg * y;
    ss  += sg;
    ts  += y;
}

// Fused kernel: blocks [0,480) do mask/dice half-planes; blocks [480,490) do embeddings.
__global__ __launch_bounds__(1024) void fused_kernel(
        const float* __restrict__ pred_masks,
        const float* __restrict__ pred_embs,
        const float* __restrict__ gt_masks,
        const int* __restrict__ perm,
        float* __restrict__ ws) {
    __shared__ float cur[M][DD];          // 20 KB (emb path)
    __shared__ float nxt[M][DD];          // 20 KB (emb path)
    __shared__ float sim[M][M + 1];       // 1.7 KB
    __shared__ float red[16][4];

    int bid = blockIdx.x;
    int tid = threadIdx.x;
    int lane = tid & 63, wid = tid >> 6;

    if (bid < NMASK) {
        // ---- mask + dice partials over half a 128x128 plane ----
        int plane = bid >> 1, half = bid & 1;
        int m = plane % M;
        int b = (plane / M) % B;
        int t = plane / (B * M);
        int n = perm[(t * B + b) * M + m];
        const float4* src = (const float4*)(pred_masks + (((size_t)b * T + t) * NN + n) * HW) + half * (HW / 8);
        const float4* tgt = (const float4*)(gt_masks   + (((size_t)b * T + t) * M  + m) * HW) + half * (HW / 8);

        float4 s0 = src[tid];
        float4 s1 = src[tid + 1024];
        float4 t0 = tgt[tid];
        float4 t1 = tgt[tid + 1024];

        float bce = 0.f, st = 0.f, ss = 0.f, ts = 0.f;
        px(s0.x, t0.x, bce, st, ss, ts);
        px(s0.y, t0.y, bce, st, ss, ts);
        px(s0.z, t0.z, bce, st, ss, ts);
        px(s0.w, t0.w, bce, st, ss, ts);
        px(s1.x, t1.x, bce, st, ss, ts);
        px(s1.y, t1.y, bce, st, ss, ts);
        px(s1.z, t1.z, bce, st, ss, ts);
        px(s1.w, t1.w, bce, st, ss, ts);

        bce = wave_reduce(bce);
        st  = wave_reduce(st);
        ss  = wave_reduce(ss);
        ts  = wave_reduce(ts);
        if (lane == 0) { red[wid][0] = bce; red[wid][1] = st; red[wid][2] = ss; red[wid][3] = ts; }
        __syncthreads();
        if (tid == 0) {
            float a0 = 0.f, a1 = 0.f, a2 = 0.f, a3 = 0.f;
            #pragma unroll
            for (int w = 0; w < 16; ++w) { a0 += red[w][0]; a1 += red[w][1]; a2 += red[w][2]; a3 += red[w][3]; }
            float* dst = ws + bid * 4;
            dst[0] = a0; dst[1] = a1; dst[2] = a2; dst[3] = a3;
        }
    } else {
        // ---- embedding losses for one (t,b) pair ----
        int e = bid - NMASK;
        int b = e % B;
        int t = e / B;                // 0..T-2

        // normalize 40 gathered embedding vectors (16 waves; 64 lanes x float4 = 256 elems)
        for (int v = wid; v < 2 * M; v += 16) {
            int tt = (v < M) ? t : (t + 1);
            int m  = (v < M) ? v : (v - M);
            int n  = perm[(tt * B + b) * M + m];
            const float4* srcp = (const float4*)(pred_embs + (((size_t)b * T + tt) * NN + n) * DD);
            float4 x = srcp[lane];
            float sq = x.x * x.x + x.y * x.y + x.z * x.z + x.w * x.w;
            sq = wave_allreduce(sq);
            float inv = fast_rcp(fmaxf(sqrtf(sq), 1e-12f));
            float* dst = (v < M) ? &cur[m][0] : &nxt[m][0];
            ((float4*)dst)[lane] = make_float4(x.x * inv, x.y * inv, x.z * inv, x.w * inv);
        }
        __syncthreads();

        // sim = cur · nxt^T  (400 dots of length 256)
        if (tid < M * M) {
            int m = tid / M, n2 = tid % M;
            const float4* cm = (const float4*)&cur[m][0];
            const float4* nn_ = (const float4*)&nxt[n2][0];
            float d = 0.f;
            #pragma unroll 8
            for (int k = 0; k < DD / 4; ++k) {
                float4 a = cm[k], c = nn_[k];
                d += a.x * c.x + a.y * c.y + a.z * c.z + a.w * c.w;
            }
            sim[m][n2] = d;
        }
        __syncthreads();

        // per-row double log-softmax, diagonal extraction
        if (tid < M) {
            int m = tid;
            float mx = -1e30f;
            #pragma unroll
            for (int n2 = 0; n2 < M; ++n2) mx = fmaxf(mx, sim[m][n2]);
            float sa = 0.f, sc = 0.f;
            #pragma unroll
            for (int n2 = 0; n2 < M; ++n2) {
                float z = sim[m][n2] - mx;
                sa += __expf(5.0f * z);     // ALPHA = 5
                sc += __expf(10.0f * z);    // 1/TEMPERATURE = 10
            }
            float zd = sim[m][m] - mx;
            sim[m][M] = __logf(sa) - 5.0f * zd;      // reuse sim row-pad as scratch? no: use red
            red[0][0] = 0.f; // (placeholder, real store below via LDS array)
            // store per-row results in sim[][] padding column
            sim[m][M] = __logf(sa) - 5.0f * zd;
            cur[0][m] = __logf(sc) - 10.0f * zd;     // reuse cur row 0 as scratch
        }
        __syncthreads();
        if (tid == 0) {
            float sm = 0.f, sct = 0.f;
            #pragma unroll
            for (int m = 0; m < M; ++m) { sm += sim[m][M]; sct += cur[0][m]; }
            ws[EMB_WS_OFF + e * 2]     = sm;   // sum of -log_softmax(ALPHA*sim) diag
            ws[EMB_WS_OFF + e * 2 + 1] = sct;  // sum of -log_softmax(sim/T) diag
        }
    }
}

__global__ __launch_bounds__(256) void reduce_kernel(const float* __restrict__ ws, float* __restrict__ out) {
    int tid = threadIdx.x;
    float bce = 0.f, dice = 0.f, match = 0.f, ctr = 0.f;
    if (tid < T * B * M) {             // 240 planes
        const float* p0 = ws + tid * 8;
        bce = p0[0] + p0[4];
        float st = p0[1] + p0[5];
        float ss = p0[2] + p0[6];
        float ts = p0[3] + p0[7];
        dice = 1.f - 2.f * st / (ss + ts + 1e-6f);
    }
    if (tid < NEMB) {
        match = ws[EMB_WS_OFF + 2 * tid];
        ctr   = ws[EMB_WS_OFF + 2 * tid + 1];
    }
    bce = wave_reduce(bce);
    dice = wave_reduce(dice);
    match = wave_reduce(match);
    ctr = wave_reduce(ctr);
    __shared__ float red[4][4];
    int lane = tid & 63, wid = tid >> 6;
    if (lane == 0) { red[wid][0] = bce; red[wid][1] = dice; red[wid][2] = match; red[wid][3] = ctr; }
    __syncthreads();
    if (tid == 0) {
        float a = 0.f, d = 0.f, mm = 0.f, c = 0.f;
        #pragma unroll
        for (int w = 0; w < 4; ++w) { a += red[w][0]; d += red[w][1]; mm += red[w][2]; c += red[w][3]; }
        float loss_mask  = a / (float)(T * B * M * HW);
        float loss_dice  = d / (float)(T * B * M);
        float loss_match = mm / (float)((T - 1) * B * M);
        float loss_ctr   = c  / (float)((T - 1) * B * M);
        out[0] = loss_mask;
        out[1] = loss_dice;
        out[2] = loss_ctr;
        out[3] = loss_match;
        out[4] = 5.0f * loss_mask + 5.0f * loss_dice + 1.0f * loss_match + 0.5f * loss_ctr;
    }
}

extern "C" void kernel_launch(void* const* d_in, const int* in_sizes, int n_in,
                              void* d_out, int out_size, void* d_ws, size_t ws_size,
                              hipStream_t stream) {
    const float* pred_masks = (const float*)d_in[0];
    const float* pred_embs  = (const float*)d_in[1];
    const float* gt_masks   = (const float*)d_in[2];
    const int*   match_perm = (const int*)d_in[3];
    float* out = (float*)d_out;
    float* ws  = (float*)d_ws;

    hipLaunchKernelGGL(fused_kernel, dim3(NMASK + NEMB), dim3(1024), 0, stream,
                       pred_masks, pred_embs, gt_masks, match_perm, ws);
    hipLaunchKernelGGL(reduce_kernel, dim3(1), dim3(256), 0, stream, ws, out);
}